// Round 12
// baseline (9809.075 us; speedup 1.0000x reference)
//
#include <hip/hip_runtime.h>

// GRUNet: 2-layer GRU (B=128, T=512, I=64, H=256) + ReLU + FC(256->2).
// Round 12: r7 (best, 3469us) reparameterized for 2 WGs/CU (TLP).
//   - 16 groups x 32 WGs x 512 thr = 512 WGs, 2/CU, 4 waves/SIMD.
//     Group owns 8 batch rows; WG owns 8 units of both layers.
//   - Per-WG work halves (4 rows/wave dot, 4 u64 sweep/thread, 25KB LDS);
//     a CU's two WGs are independent -> spin/barrier/LDS latency of one
//     overlaps the other's dot.
//   - __launch_bounds__(512,4) pins VGPR<=128: 512-WG co-residency is
//     correctness-critical.
//   - Sweep u64s remapped adjacent -> unpack is one ds_write_b128.
//   - Everything else r7 verbatim: mantissa-tag dataflow (2 LSBs, ring 3,
//     tag cycle 4), register-resident weights, 3 barriers/step, no flags
//     (r10/r11 proved WAR-safety via value causality).

namespace {
constexpr int kB = 128, kT = 512, kI = 64, kH = 256, kBH = kB * kH;
constexpr int RPG = 8, NWG = 512, NT = 512;

// activation stage: [kseg 8][row 8][32], row stride 36, kseg stride 292
constexpr int SRS = 36;
constexpr int SKS = 8 * SRS + 4;           // 292 (mod-32 = 4: kseg bank spread)
constexpr int O_S0 = 0;                    // h0(s-1) stage [8][8][36]
constexpr int O_S1 = O_S0 + 8 * SKS;       // h1(s-2) stage
constexpr int O_X  = O_S1 + 8 * SKS;       // [8][68] x(s)
constexpr int O_PB = O_X + RPG * 68;       // partials [4][8][36]
constexpr int PBN  = 4 * 8 * 36;           // 1152
constexpr int LDSF = O_PB + PBN;           // 6368 floats = 25472 B
}

using ull = unsigned long long;
using u32 = unsigned;

__device__ __forceinline__ float sigf(float v) { return 1.0f / (1.0f + expf(-v)); }
__device__ __forceinline__ float dot4(const float4 a, const float4 b) {
  return a.x * b.x + a.y * b.y + a.z * b.z + a.w * b.w;
}
__device__ __forceinline__ float red8(float v) {   // sum over kseg lanes (bits 3..5)
  v += __shfl_xor(v, 8);
  v += __shfl_xor(v, 16);
  v += __shfl_xor(v, 32);
  return v;
}
#define F4(p) (*(const float4*)(p))
#define AL(p)    __hip_atomic_load((p), __ATOMIC_RELAXED, __HIP_MEMORY_SCOPE_AGENT)
#define AS(p, v) __hip_atomic_store((p), (v), __ATOMIC_RELAXED, __HIP_MEMORY_SCOPE_AGENT)

__global__ __launch_bounds__(NT, 4) void gru_persistent(
    const float* __restrict__ x,
    const float* __restrict__ wih0, const float* __restrict__ whh0,
    const float* __restrict__ bih0, const float* __restrict__ bhh0,
    const float* __restrict__ wih1, const float* __restrict__ whh1,
    const float* __restrict__ bih1, const float* __restrict__ bhh1,
    const float* __restrict__ fcw, const float* __restrict__ fcb,
    u32* __restrict__ h0w,    // [3][B][H] tagged dwords
    u32* __restrict__ h1w,    // [3][B][H] tagged dwords
    float* __restrict__ out)
{
  __shared__ float lds[LDSF];

  const int bid = blockIdx.x;
  const int g   = bid >> 5;            // group 0..15
  const int wg  = bid & 31;
  const int tid = threadIdx.x;
  const int r0  = g * RPG;             // 8 rows per group
  const int j0  = wg * 8;

  const int wave = tid >> 6, lane = tid & 63;
  const int lay  = wave >> 2;          // waves 0-3: l0, 4-7: l1
  const int fam  = (wave >> 1) & 1;
  const int rh   = wave & 1;
  const int ju   = lane & 7;
  const int ks   = lane >> 3;
  const int jg   = j0 + ju;

  // zero partial buffer once (unwritten slots must stay 0 forever)
  for (int i = tid; i < PBN; i += NT) lds[O_PB + i] = 0.f;

  // ---- weight slices into registers (once) — r7 verbatim ----
  float4 wr0[8], wr1[8], wr2[8];
  if (lay == 0) {
    if (fam == 0) {
#define L0F0(wrg, gg) { \
      const float* wi = wih0 + (size_t)((gg) * kH + jg) * kI + ks * 8;   \
      const float* wh = whh0 + (size_t)((gg) * kH + jg) * kH + ks * 32;  \
      wrg[0] = F4(wi); wrg[1] = F4(wi + 4);                              \
      wrg[2] = F4(wh); wrg[3] = F4(wh + 4); wrg[4] = F4(wh + 8); }
      L0F0(wr0, 0) L0F0(wr1, 1) L0F0(wr2, 2)
    } else {
#define L0F1(wrg, gg) { \
      const float* wh = whh0 + (size_t)((gg) * kH + jg) * kH + ks * 32 + 12; \
      wrg[0] = F4(wh); wrg[1] = F4(wh + 4); wrg[2] = F4(wh + 8);             \
      wrg[3] = F4(wh + 12); wrg[4] = F4(wh + 16); }
      L0F1(wr0, 0) L0F1(wr1, 1) L0F1(wr2, 2)
    }
  } else {
    const float* ws = fam ? whh1 : wih1;
#define L1W(wrg, gg) { \
    const float* wp = ws + (size_t)((gg) * kH + jg) * kH + ks * 32;          \
    wrg[0] = F4(wp);      wrg[1] = F4(wp + 4);  wrg[2] = F4(wp + 8);         \
    wrg[3] = F4(wp + 12); wrg[4] = F4(wp + 16); wrg[5] = F4(wp + 20);        \
    wrg[6] = F4(wp + 24); wrg[7] = F4(wp + 28); }
    L1W(wr0, 0) L1W(wr1, 1) L1W(wr2, 2)
  }

  // ---- finisher constants (tid < 128: layf = tid>>6, 8 rows x 8 units) ----
  float fb_r = 0.f, fb_z = 0.f, fn_i = 0.f, fn_h = 0.f;
  if (tid < 128) {
    const int layf = tid >> 6, uf = tid & 7, jf = j0 + uf;
    const float* bi = layf ? bih1 : bih0;
    const float* bh = layf ? bhh1 : bhh0;
    fb_r = bi[jf] + bh[jf];
    fb_z = bi[kH + jf] + bh[kH + jf];
    fn_i = bi[2 * kH + jf];
    fn_h = bh[2 * kH + jf];
  }

  // sweep: thread owns u64 pair {2*tid, 2*tid+1} of 1024 u64 (8 rows x 128)
  const int SRO = tid >> 6;            // staged row 0..7
  const int SK2 = (2 * tid) & 127;     // even u64 col -> 16B-aligned pair

  __syncthreads();

  // ---- 513 steps: sweep -> sync -> dot -> sync -> finish -> sync ----
  for (int s = 0; s <= kT; ++s) {
    const int slot0 = (s + 2) % 3;           // h0(s-1)
    const int slot1 = (s + 1) % 3;           // h1(s-2)
    const u32 e0 = (u32)(s & 3);
    const u32 e1 = (u32)((s - 1) & 3);

    // x(s) pre-issue (plain loads)
    float4 xv = {};
    if (s < kT && tid < 128) {
      const int ro = tid >> 4, c4 = (tid & 15) * 4;
      xv = F4(x + (size_t)(r0 + ro) * kT * kI + (size_t)s * kI + c4);
    }

    // sweep-poll h data (pre-issue, retry whole sweep on tag miss)
    const ull* A0 = (const ull*)(h0w + (size_t)slot0 * kBH +
                                 (size_t)(r0 + SRO) * kH) + SK2;
    ull v00 = AL(A0), v01 = AL(A0 + 1);
    const ull* A1 = nullptr;
    ull v10 = 0, v11 = 0;
    if (s >= 1) {
      A1 = (const ull*)(h1w + (size_t)slot1 * kBH +
                        (size_t)(r0 + SRO) * kH) + SK2;
      v10 = AL(A1); v11 = AL(A1 + 1);
    }
    for (;;) {
      u32 bad = ((u32)v00 ^ e0) | ((u32)(v00 >> 32) ^ e0) |
                ((u32)v01 ^ e0) | ((u32)(v01 >> 32) ^ e0);
      if (s >= 1)
        bad |= ((u32)v10 ^ e1) | ((u32)(v10 >> 32) ^ e1) |
               ((u32)v11 ^ e1) | ((u32)(v11 >> 32) ^ e1);
      if (!(bad & 3u)) break;
      __builtin_amdgcn_s_sleep(1);
      v00 = AL(A0); v01 = AL(A0 + 1);
      if (s >= 1) { v10 = AL(A1); v11 = AL(A1 + 1); }
    }
    // unpack: one b128 write per buffer (pair is 16B-aligned, same kseg)
    {
      const int ksg = SK2 >> 4, off = (SK2 * 2) & 31;
      float4 f0;
      f0.x = __uint_as_float((u32)v00); f0.y = __uint_as_float((u32)(v00 >> 32));
      f0.z = __uint_as_float((u32)v01); f0.w = __uint_as_float((u32)(v01 >> 32));
      *(float4*)(lds + O_S0 + ksg * SKS + SRO * SRS + off) = f0;
      if (s >= 1) {
        float4 f1;
        f1.x = __uint_as_float((u32)v10); f1.y = __uint_as_float((u32)(v10 >> 32));
        f1.z = __uint_as_float((u32)v11); f1.w = __uint_as_float((u32)(v11 >> 32));
        *(float4*)(lds + O_S1 + ksg * SKS + SRO * SRS + off) = f1;
      }
    }
    if (s < kT && tid < 128) {
      const int ro = tid >> 4, c4 = (tid & 15) * 4;
      *(float4*)(lds + O_X + ro * 68 + c4) = xv;
    }
    __syncthreads();

    // dot phase (r7 verbatim, 4 rows per wave)
    const bool wact = lay ? (s >= 1) : (s < kT);
    if (wact) {
      float prr[4], pzz[4], pni[4], pnh[4];
      #pragma unroll
      for (int r = 0; r < 4; ++r) {
        const int ro = rh * 4 + r;
        float pr = 0.f, pz = 0.f, pxi = 0.f, pxh = 0.f;
        if (lay == 0) {
          if (fam == 0) {
            const float* ax = lds + O_X + ro * 68 + ks * 8;
            const float4 x0 = F4(ax), x1 = F4(ax + 4);
            pr  += dot4(x0, wr0[0]) + dot4(x1, wr0[1]);
            pz  += dot4(x0, wr1[0]) + dot4(x1, wr1[1]);
            pxi += dot4(x0, wr2[0]) + dot4(x1, wr2[1]);
            const float* ah = lds + O_S0 + ks * SKS + ro * SRS;
            #pragma unroll
            for (int i = 0; i < 3; ++i) {
              const float4 hv = F4(ah + i * 4);
              pr  += dot4(hv, wr0[2 + i]);
              pz  += dot4(hv, wr1[2 + i]);
              pxh += dot4(hv, wr2[2 + i]);
            }
          } else {
            const float* ah = lds + O_S0 + ks * SKS + ro * SRS + 12;
            #pragma unroll
            for (int i = 0; i < 5; ++i) {
              const float4 hv = F4(ah + i * 4);
              pr  += dot4(hv, wr0[i]);
              pz  += dot4(hv, wr1[i]);
              pxh += dot4(hv, wr2[i]);
            }
          }
        } else {
          const float* aa = lds + (fam ? O_S1 : O_S0) + ks * SKS + ro * SRS;
          #pragma unroll
          for (int i = 0; i < 8; ++i) {
            const float4 av = F4(aa + i * 4);
            pr += dot4(av, wr0[i]);
            pz += dot4(av, wr1[i]);
            if (fam) pxh += dot4(av, wr2[i]);
            else     pxi += dot4(av, wr2[i]);
          }
        }
        prr[r] = pr; pzz[r] = pz; pni[r] = pxi; pnh[r] = pxh;
      }
      #pragma unroll
      for (int r = 0; r < 4; ++r) { prr[r] = red8(prr[r]); pzz[r] = red8(pzz[r]); }
      if (lay == 0 && fam == 0) {
        #pragma unroll
        for (int r = 0; r < 4; ++r) { pni[r] = red8(pni[r]); pnh[r] = red8(pnh[r]); }
      } else if (fam == 0) {
        #pragma unroll
        for (int r = 0; r < 4; ++r) pni[r] = red8(pni[r]);
      } else {
        #pragma unroll
        for (int r = 0; r < 4; ++r) pnh[r] = red8(pnh[r]);
      }
      if (ks == 0) {
        #pragma unroll
        for (int r = 0; r < 4; ++r) {
          const int ro = rh * 4 + r;
          float* pb = lds + O_PB + ((wave >> 1) * 8 + ro) * SRS + ju;
          pb[0] = prr[r]; pb[8] = pzz[r];
          if (lay == 0 && fam == 0) { pb[16] = pni[r]; pb[24] = pnh[r]; }
          else if (fam == 0)          pb[16] = pni[r];
          else                        pb[24] = pnh[r];
        }
      }
    }
    __syncthreads();

    // finish: gates + tagged publish (128 threads)
    if (tid < 128) {
      const int layf = tid >> 6;
      const bool act = layf ? (s >= 1) : (s < kT);
      if (act) {
        const int local = tid & 63, rof = local >> 3, uf = local & 7;
        const int jf = j0 + uf;
        const float* p0 = lds + O_PB + ((layf * 2) * 8 + rof) * SRS + uf;
        const float* p1 = p0 + 8 * SRS;
        const float rr = sigf(p0[0] + p1[0] + fb_r);
        const float zz = sigf(p0[8] + p1[8] + fb_z);
        const float nn = tanhf(p0[16] + p1[16] + fn_i +
                               rr * (p0[24] + p1[24] + fn_h));
        const float hp = lds[(layf ? O_S1 : O_S0) +
                             (jf >> 5) * SKS + rof * SRS + (jf & 31)];
        const float hv = (1.f - zz) * nn + zz * hp;
        // h0(s) -> slot s%3, tag (s+1)&3; h1(s-1) -> slot (s-1)%3, tag s&3
        const int slot = layf ? ((s - 1) % 3) : (s % 3);
        const u32 tag = layf ? (u32)(s & 3) : (u32)((s + 1) & 3);
        const u32 bits = (__float_as_uint(hv) & ~3u) | tag;
        u32* hw = (layf ? h1w : h0w) + (size_t)slot * kBH +
                  (size_t)(r0 + rof) * kH + jf;
        AS(hw, bits);
      }
    }
    __syncthreads();
  }

  // ---- FC epilogue: group's WG0; h1(T-1) slot (kT-1)%3=1, tag kT&3=0 ----
  if (wg == 0 && tid < 128) {
    const int rv = tid >> 4, o = (tid >> 3) & 1, kseg = tid & 7;
    const u32* hf = h1w + (size_t)((kT - 1) % 3) * kBH + (size_t)(r0 + rv) * kH;
    const float* wfc = fcw + (size_t)o * kH;
    float acc = 0.f;
    for (int k = kseg * 32; k < kseg * 32 + 32; ++k) {
      u32 b;
      do {
        b = AL(hf + k);
      } while ((b & 3u) != (u32)(kT & 3));
      acc += fmaxf(__uint_as_float(b), 0.f) * wfc[k];
    }
    acc += __shfl_xor(acc, 1);
    acc += __shfl_xor(acc, 2);
    acc += __shfl_xor(acc, 4);
    if (kseg == 0) out[(r0 + rv) * 2 + o] = acc + fcb[o];
  }
}

extern "C" void kernel_launch(void* const* d_in, const int* in_sizes, int n_in,
                              void* d_out, int out_size, void* d_ws, size_t ws_size,
                              hipStream_t stream) {
  const float* x    = (const float*)d_in[0];
  const float* wih0 = (const float*)d_in[1];
  const float* whh0 = (const float*)d_in[2];
  const float* bih0 = (const float*)d_in[3];
  const float* bhh0 = (const float*)d_in[4];
  const float* wih1 = (const float*)d_in[5];
  const float* whh1 = (const float*)d_in[6];
  const float* bih1 = (const float*)d_in[7];
  const float* bhh1 = (const float*)d_in[8];
  const float* fcw  = (const float*)d_in[9];
  const float* fcb  = (const float*)d_in[10];

  u32* h0w = (u32*)d_ws;                 // [3][B][H] tagged
  u32* h1w = h0w + 3 * kBH;              // [3][B][H] tagged
  float* out = (float*)d_out;

  // zero tagged h buffers (tag 0 == t=-1 state) every call
  hipMemsetAsync(d_ws, 0, (size_t)(6 * kBH) * sizeof(u32), stream);

  gru_persistent<<<NWG, NT, 0, stream>>>(
      x, wih0, whh0, bih0, bhh0, wih1, whh1, bih1, bhh1,
      fcw, fcb, h0w, h1w, out);
}

// Round 13
// 4435.910 us; speedup vs baseline: 2.2113x; 2.2113x over previous
//
#include <hip/hip_runtime.h>

// GRUNet: 2-layer GRU (B=128, T=512, I=64, H=256) + ReLU + FC(256->2).
// Round 13: r12 with the launch-bounds trap fixed.
//   r12 post-mortem: __launch_bounds__(512,4) acted as CUDA-style
//   min-4-BLOCKS/CU -> 8 waves/SIMD -> VGPR capped at 64 -> the 96
//   weight VGPRs spilled to scratch (FETCH 6.5GB, VALUBusy 15%).
//   Fix: __launch_bounds__(512,2) (r7/r10/r11-proven: compiles to
//   124-128 VGPR). With 25.5KB LDS this permits 2 WGs/CU = 4 waves/SIMD.
//   - 16 groups x 32 WGs x 512 thr = 512 WGs. Group owns 8 batch rows;
//     WG owns 8 units of both layers; register-resident weight slices.
//   - Mantissa-tag dataflow (2 LSBs, ring 3, tag cycle 4), 3 barriers/
//     step, no WAR flags (value-causality; r10/r11-validated).
//   - No-deadlock argument: groups spin only within themselves; >=7 full
//     groups resident worst-case; complete groups exit and free CUs.

namespace {
constexpr int kB = 128, kT = 512, kI = 64, kH = 256, kBH = kB * kH;
constexpr int RPG = 8, NWG = 512, NT = 512;

// activation stage: [kseg 8][row 8][32], row stride 36, kseg stride 292
constexpr int SRS = 36;
constexpr int SKS = 8 * SRS + 4;           // 292
constexpr int O_S0 = 0;                    // h0(s-1) stage
constexpr int O_S1 = O_S0 + 8 * SKS;       // h1(s-2) stage
constexpr int O_X  = O_S1 + 8 * SKS;       // [8][68] x(s)
constexpr int O_PB = O_X + RPG * 68;       // partials [4][8][36]
constexpr int PBN  = 4 * 8 * 36;           // 1152
constexpr int LDSF = O_PB + PBN;           // 6368 floats = 25472 B
}

using ull = unsigned long long;
using u32 = unsigned;

__device__ __forceinline__ float sigf(float v) { return 1.0f / (1.0f + expf(-v)); }
__device__ __forceinline__ float dot4(const float4 a, const float4 b) {
  return a.x * b.x + a.y * b.y + a.z * b.z + a.w * b.w;
}
__device__ __forceinline__ float red8(float v) {   // sum over kseg lanes (bits 3..5)
  v += __shfl_xor(v, 8);
  v += __shfl_xor(v, 16);
  v += __shfl_xor(v, 32);
  return v;
}
#define F4(p) (*(const float4*)(p))
#define AL(p)    __hip_atomic_load((p), __ATOMIC_RELAXED, __HIP_MEMORY_SCOPE_AGENT)
#define AS(p, v) __hip_atomic_store((p), (v), __ATOMIC_RELAXED, __HIP_MEMORY_SCOPE_AGENT)

__global__ __launch_bounds__(NT, 2) void gru_persistent(
    const float* __restrict__ x,
    const float* __restrict__ wih0, const float* __restrict__ whh0,
    const float* __restrict__ bih0, const float* __restrict__ bhh0,
    const float* __restrict__ wih1, const float* __restrict__ whh1,
    const float* __restrict__ bih1, const float* __restrict__ bhh1,
    const float* __restrict__ fcw, const float* __restrict__ fcb,
    u32* __restrict__ h0w,    // [3][B][H] tagged dwords
    u32* __restrict__ h1w,    // [3][B][H] tagged dwords
    float* __restrict__ out)
{
  __shared__ float lds[LDSF];

  const int bid = blockIdx.x;
  const int g   = bid >> 5;            // group 0..15
  const int wg  = bid & 31;
  const int tid = threadIdx.x;
  const int r0  = g * RPG;             // 8 rows per group
  const int j0  = wg * 8;

  const int wave = tid >> 6, lane = tid & 63;
  const int lay  = wave >> 2;          // waves 0-3: l0, 4-7: l1
  const int fam  = (wave >> 1) & 1;
  const int rh   = wave & 1;
  const int ju   = lane & 7;
  const int ks   = lane >> 3;
  const int jg   = j0 + ju;

  // zero partial buffer once (unwritten slots must stay 0 forever)
  for (int i = tid; i < PBN; i += NT) lds[O_PB + i] = 0.f;

  // ---- weight slices into registers (once) — r7 verbatim ----
  float4 wr0[8], wr1[8], wr2[8];
  if (lay == 0) {
    if (fam == 0) {
#define L0F0(wrg, gg) { \
      const float* wi = wih0 + (size_t)((gg) * kH + jg) * kI + ks * 8;   \
      const float* wh = whh0 + (size_t)((gg) * kH + jg) * kH + ks * 32;  \
      wrg[0] = F4(wi); wrg[1] = F4(wi + 4);                              \
      wrg[2] = F4(wh); wrg[3] = F4(wh + 4); wrg[4] = F4(wh + 8); }
      L0F0(wr0, 0) L0F0(wr1, 1) L0F0(wr2, 2)
    } else {
#define L0F1(wrg, gg) { \
      const float* wh = whh0 + (size_t)((gg) * kH + jg) * kH + ks * 32 + 12; \
      wrg[0] = F4(wh); wrg[1] = F4(wh + 4); wrg[2] = F4(wh + 8);             \
      wrg[3] = F4(wh + 12); wrg[4] = F4(wh + 16); }
      L0F1(wr0, 0) L0F1(wr1, 1) L0F1(wr2, 2)
    }
  } else {
    const float* ws = fam ? whh1 : wih1;
#define L1W(wrg, gg) { \
    const float* wp = ws + (size_t)((gg) * kH + jg) * kH + ks * 32;          \
    wrg[0] = F4(wp);      wrg[1] = F4(wp + 4);  wrg[2] = F4(wp + 8);         \
    wrg[3] = F4(wp + 12); wrg[4] = F4(wp + 16); wrg[5] = F4(wp + 20);        \
    wrg[6] = F4(wp + 24); wrg[7] = F4(wp + 28); }
    L1W(wr0, 0) L1W(wr1, 1) L1W(wr2, 2)
  }

  // ---- finisher constants (tid < 128: layf = tid>>6, 8 rows x 8 units) ----
  float fb_r = 0.f, fb_z = 0.f, fn_i = 0.f, fn_h = 0.f;
  if (tid < 128) {
    const int layf = tid >> 6, uf = tid & 7, jf = j0 + uf;
    const float* bi = layf ? bih1 : bih0;
    const float* bh = layf ? bhh1 : bhh0;
    fb_r = bi[jf] + bh[jf];
    fb_z = bi[kH + jf] + bh[kH + jf];
    fn_i = bi[2 * kH + jf];
    fn_h = bh[2 * kH + jf];
  }

  // sweep: thread owns u64 pair {2*tid, 2*tid+1} of 1024 u64 (8 rows x 128)
  const int SRO = tid >> 6;            // staged row 0..7
  const int SK2 = (2 * tid) & 127;     // even u64 col -> 16B-aligned pair

  __syncthreads();

  // ---- 513 steps: sweep -> sync -> dot -> sync -> finish -> sync ----
  for (int s = 0; s <= kT; ++s) {
    const int slot0 = (s + 2) % 3;           // h0(s-1)
    const int slot1 = (s + 1) % 3;           // h1(s-2)
    const u32 e0 = (u32)(s & 3);
    const u32 e1 = (u32)((s - 1) & 3);

    // x(s) pre-issue (plain loads)
    float4 xv = {};
    if (s < kT && tid < 128) {
      const int ro = tid >> 4, c4 = (tid & 15) * 4;
      xv = F4(x + (size_t)(r0 + ro) * kT * kI + (size_t)s * kI + c4);
    }

    // sweep-poll h data (pre-issue, retry whole sweep on tag miss)
    const ull* A0 = (const ull*)(h0w + (size_t)slot0 * kBH +
                                 (size_t)(r0 + SRO) * kH) + SK2;
    ull v00 = AL(A0), v01 = AL(A0 + 1);
    const ull* A1 = nullptr;
    ull v10 = 0, v11 = 0;
    if (s >= 1) {
      A1 = (const ull*)(h1w + (size_t)slot1 * kBH +
                        (size_t)(r0 + SRO) * kH) + SK2;
      v10 = AL(A1); v11 = AL(A1 + 1);
    }
    for (;;) {
      u32 bad = ((u32)v00 ^ e0) | ((u32)(v00 >> 32) ^ e0) |
                ((u32)v01 ^ e0) | ((u32)(v01 >> 32) ^ e0);
      if (s >= 1)
        bad |= ((u32)v10 ^ e1) | ((u32)(v10 >> 32) ^ e1) |
               ((u32)v11 ^ e1) | ((u32)(v11 >> 32) ^ e1);
      if (!(bad & 3u)) break;
      __builtin_amdgcn_s_sleep(1);
      v00 = AL(A0); v01 = AL(A0 + 1);
      if (s >= 1) { v10 = AL(A1); v11 = AL(A1 + 1); }
    }
    // unpack: one b128 write per buffer (pair is 16B-aligned, same kseg)
    {
      const int ksg = SK2 >> 4, off = (SK2 * 2) & 31;
      float4 f0;
      f0.x = __uint_as_float((u32)v00); f0.y = __uint_as_float((u32)(v00 >> 32));
      f0.z = __uint_as_float((u32)v01); f0.w = __uint_as_float((u32)(v01 >> 32));
      *(float4*)(lds + O_S0 + ksg * SKS + SRO * SRS + off) = f0;
      if (s >= 1) {
        float4 f1;
        f1.x = __uint_as_float((u32)v10); f1.y = __uint_as_float((u32)(v10 >> 32));
        f1.z = __uint_as_float((u32)v11); f1.w = __uint_as_float((u32)(v11 >> 32));
        *(float4*)(lds + O_S1 + ksg * SKS + SRO * SRS + off) = f1;
      }
    }
    if (s < kT && tid < 128) {
      const int ro = tid >> 4, c4 = (tid & 15) * 4;
      *(float4*)(lds + O_X + ro * 68 + c4) = xv;
    }
    __syncthreads();

    // dot phase (r7 verbatim, 4 rows per wave)
    const bool wact = lay ? (s >= 1) : (s < kT);
    if (wact) {
      float prr[4], pzz[4], pni[4], pnh[4];
      #pragma unroll
      for (int r = 0; r < 4; ++r) {
        const int ro = rh * 4 + r;
        float pr = 0.f, pz = 0.f, pxi = 0.f, pxh = 0.f;
        if (lay == 0) {
          if (fam == 0) {
            const float* ax = lds + O_X + ro * 68 + ks * 8;
            const float4 x0 = F4(ax), x1 = F4(ax + 4);
            pr  += dot4(x0, wr0[0]) + dot4(x1, wr0[1]);
            pz  += dot4(x0, wr1[0]) + dot4(x1, wr1[1]);
            pxi += dot4(x0, wr2[0]) + dot4(x1, wr2[1]);
            const float* ah = lds + O_S0 + ks * SKS + ro * SRS;
            #pragma unroll
            for (int i = 0; i < 3; ++i) {
              const float4 hv = F4(ah + i * 4);
              pr  += dot4(hv, wr0[2 + i]);
              pz  += dot4(hv, wr1[2 + i]);
              pxh += dot4(hv, wr2[2 + i]);
            }
          } else {
            const float* ah = lds + O_S0 + ks * SKS + ro * SRS + 12;
            #pragma unroll
            for (int i = 0; i < 5; ++i) {
              const float4 hv = F4(ah + i * 4);
              pr  += dot4(hv, wr0[i]);
              pz  += dot4(hv, wr1[i]);
              pxh += dot4(hv, wr2[i]);
            }
          }
        } else {
          const float* aa = lds + (fam ? O_S1 : O_S0) + ks * SKS + ro * SRS;
          #pragma unroll
          for (int i = 0; i < 8; ++i) {
            const float4 av = F4(aa + i * 4);
            pr += dot4(av, wr0[i]);
            pz += dot4(av, wr1[i]);
            if (fam) pxh += dot4(av, wr2[i]);
            else     pxi += dot4(av, wr2[i]);
          }
        }
        prr[r] = pr; pzz[r] = pz; pni[r] = pxi; pnh[r] = pxh;
      }
      #pragma unroll
      for (int r = 0; r < 4; ++r) { prr[r] = red8(prr[r]); pzz[r] = red8(pzz[r]); }
      if (lay == 0 && fam == 0) {
        #pragma unroll
        for (int r = 0; r < 4; ++r) { pni[r] = red8(pni[r]); pnh[r] = red8(pnh[r]); }
      } else if (fam == 0) {
        #pragma unroll
        for (int r = 0; r < 4; ++r) pni[r] = red8(pni[r]);
      } else {
        #pragma unroll
        for (int r = 0; r < 4; ++r) pnh[r] = red8(pnh[r]);
      }
      if (ks == 0) {
        #pragma unroll
        for (int r = 0; r < 4; ++r) {
          const int ro = rh * 4 + r;
          float* pb = lds + O_PB + ((wave >> 1) * 8 + ro) * SRS + ju;
          pb[0] = prr[r]; pb[8] = pzz[r];
          if (lay == 0 && fam == 0) { pb[16] = pni[r]; pb[24] = pnh[r]; }
          else if (fam == 0)          pb[16] = pni[r];
          else                        pb[24] = pnh[r];
        }
      }
    }
    __syncthreads();

    // finish: gates + tagged publish (128 threads)
    if (tid < 128) {
      const int layf = tid >> 6;
      const bool act = layf ? (s >= 1) : (s < kT);
      if (act) {
        const int local = tid & 63, rof = local >> 3, uf = local & 7;
        const int jf = j0 + uf;
        const float* p0 = lds + O_PB + ((layf * 2) * 8 + rof) * SRS + uf;
        const float* p1 = p0 + 8 * SRS;
        const float rr = sigf(p0[0] + p1[0] + fb_r);
        const float zz = sigf(p0[8] + p1[8] + fb_z);
        const float nn = tanhf(p0[16] + p1[16] + fn_i +
                               rr * (p0[24] + p1[24] + fn_h));
        const float hp = lds[(layf ? O_S1 : O_S0) +
                             (jf >> 5) * SKS + rof * SRS + (jf & 31)];
        const float hv = (1.f - zz) * nn + zz * hp;
        // h0(s) -> slot s%3, tag (s+1)&3; h1(s-1) -> slot (s-1)%3, tag s&3
        const int slot = layf ? ((s - 1) % 3) : (s % 3);
        const u32 tag = layf ? (u32)(s & 3) : (u32)((s + 1) & 3);
        const u32 bits = (__float_as_uint(hv) & ~3u) | tag;
        u32* hw = (layf ? h1w : h0w) + (size_t)slot * kBH +
                  (size_t)(r0 + rof) * kH + jf;
        AS(hw, bits);
      }
    }
    __syncthreads();
  }

  // ---- FC epilogue: group's WG0; h1(T-1) slot (kT-1)%3=1, tag kT&3=0 ----
  if (wg == 0 && tid < 128) {
    const int rv = tid >> 4, o = (tid >> 3) & 1, kseg = tid & 7;
    const u32* hf = h1w + (size_t)((kT - 1) % 3) * kBH + (size_t)(r0 + rv) * kH;
    const float* wfc = fcw + (size_t)o * kH;
    float acc = 0.f;
    for (int k = kseg * 32; k < kseg * 32 + 32; ++k) {
      u32 b;
      do {
        b = AL(hf + k);
      } while ((b & 3u) != (u32)(kT & 3));
      acc += fmaxf(__uint_as_float(b), 0.f) * wfc[k];
    }
    acc += __shfl_xor(acc, 1);
    acc += __shfl_xor(acc, 2);
    acc += __shfl_xor(acc, 4);
    if (kseg == 0) out[(r0 + rv) * 2 + o] = acc + fcb[o];
  }
}

extern "C" void kernel_launch(void* const* d_in, const int* in_sizes, int n_in,
                              void* d_out, int out_size, void* d_ws, size_t ws_size,
                              hipStream_t stream) {
  const float* x    = (const float*)d_in[0];
  const float* wih0 = (const float*)d_in[1];
  const float* whh0 = (const float*)d_in[2];
  const float* bih0 = (const float*)d_in[3];
  const float* bhh0 = (const float*)d_in[4];
  const float* wih1 = (const float*)d_in[5];
  const float* whh1 = (const float*)d_in[6];
  const float* bih1 = (const float*)d_in[7];
  const float* bhh1 = (const float*)d_in[8];
  const float* fcw  = (const float*)d_in[9];
  const float* fcb  = (const float*)d_in[10];

  u32* h0w = (u32*)d_ws;                 // [3][B][H] tagged
  u32* h1w = h0w + 3 * kBH;              // [3][B][H] tagged
  float* out = (float*)d_out;

  // zero tagged h buffers (tag 0 == t=-1 state) every call
  hipMemsetAsync(d_ws, 0, (size_t)(6 * kBH) * sizeof(u32), stream);

  gru_persistent<<<NWG, NT, 0, stream>>>(
      x, wih0, whh0, bih0, bhh0, wih1, whh1, bih1, bhh1,
      fcw, fcb, h0w, h1w, out);
}